// Round 1
// baseline (1478.581 us; speedup 1.0000x reference)
//
#include <hip/hip_runtime.h>
#include <math.h>

#define CIN 256
#define COUT 256
#define HH 64
#define WW 64
#define BB 8
#define HW 4096
#define KDIM 2304              // 9*256
#define NPIX9 (BB*9*HH*WW)     // 294912

// ws layout (float-element offsets)
#define WS_BMAT 0
#define WS_REC  (2304*256)     // 589824

// ---------------------------------------------------------------------------
// K0: weight (Cout,Cin,3,3) -> Bmat[k][oc], k = tap*256 + c
// ---------------------------------------------------------------------------
__global__ void transpose_weights(const float* __restrict__ weight,
                                  float* __restrict__ Bmat) {
    int k = blockIdx.x;            // 0..2303
    int oc = threadIdx.x;          // 0..255
    int tap = k >> 8;
    int c = k & 255;
    Bmat[(size_t)k * 256 + oc] = weight[(size_t)oc * KDIM + c * 9 + tap];
}

// ---------------------------------------------------------------------------
// K1: offset conv (3x3, pad 1) -> per-(pixel,tap) sampling records
//   4 clamped flat offsets into a (H,W) slice + 4 mask-folded bilinear weights
// ---------------------------------------------------------------------------
__global__ __launch_bounds__(256) void offset_conv(
    const float* __restrict__ x, const float* __restrict__ ow,
    const float* __restrict__ ob,
    int* __restrict__ off00, int* __restrict__ off01,
    int* __restrict__ off10, int* __restrict__ off11,
    float* __restrict__ ww00, float* __restrict__ ww01,
    float* __restrict__ ww10, float* __restrict__ ww11)
{
    int blk = blockIdx.x;          // b*64 + h
    int b = blk >> 6, h = blk & 63;
    int t = threadIdx.x;
    int w = t & 63;
    int cg = t >> 6;               // wave id 0..3 (uniform within wave)
    cg = __builtin_amdgcn_readfirstlane(cg);   // make weight addrs scalar

    float acc[27];
    #pragma unroll
    for (int i = 0; i < 27; ++i) acc[i] = 0.f;

    const float* xb = x + (size_t)b * CIN * HW;
    for (int ci = 0; ci < 64; ++ci) {
        int c = cg * 64 + ci;
        const float* xs = xb + (size_t)c * HW;
        float xv[9];
        #pragma unroll
        for (int ki = 0; ki < 3; ++ki) {
            int yy = h - 1 + ki;
            bool vy = (yy >= 0) & (yy < HH);
            #pragma unroll
            for (int kj = 0; kj < 3; ++kj) {
                int xx = w - 1 + kj;
                bool vx = (xx >= 0) & (xx < WW);
                xv[ki * 3 + kj] = (vy & vx) ? xs[yy * WW + xx] : 0.f;
            }
        }
        const float* wp = ow + c * 9;
        #pragma unroll
        for (int oc = 0; oc < 27; ++oc) {
            #pragma unroll
            for (int tap = 0; tap < 9; ++tap)
                acc[oc] = fmaf(xv[tap], wp[(size_t)oc * KDIM + tap], acc[oc]);
        }
    }

    __shared__ float red[4][27][64];
    #pragma unroll
    for (int oc = 0; oc < 27; ++oc) red[cg][oc][w] = acc[oc];
    __syncthreads();

    for (int rep = 0; rep < 3; ++rep) {
        int idx = rep * 256 + t;   // 0..575 = 9 taps * 64 w
        if (idx < 576) {
            int k = idx >> 6, w2 = idx & 63;
            float dy = red[0][2*k][w2] + red[1][2*k][w2]
                     + red[2][2*k][w2] + red[3][2*k][w2] + ob[2*k];
            float dx = red[0][2*k+1][w2] + red[1][2*k+1][w2]
                     + red[2][2*k+1][w2] + red[3][2*k+1][w2] + ob[2*k+1];
            float mv = red[0][18+k][w2] + red[1][18+k][w2]
                     + red[2][18+k][w2] + red[3][18+k][w2] + ob[18+k];
            float m = 1.f / (1.f + expf(-mv));

            float py = dy + (float)(h - 1 + k / 3);
            float px = dx + (float)(w2 - 1 + k % 3);
            float y0f = floorf(py), x0f = floorf(px);
            float wy1 = py - y0f, wx1 = px - x0f;
            float wy0 = 1.f - wy1, wx0 = 1.f - wx1;
            int iy0 = (int)y0f, ix0 = (int)x0f;
            int iy1 = iy0 + 1, ix1 = ix0 + 1;
            bool vy0 = (iy0 >= 0) & (iy0 < HH);
            bool vy1 = (iy1 >= 0) & (iy1 < HH);
            bool vx0 = (ix0 >= 0) & (ix0 < WW);
            bool vx1 = (ix1 >= 0) & (ix1 < WW);
            int cy0 = min(max(iy0, 0), HH - 1), cy1 = min(max(iy1, 0), HH - 1);
            int cx0 = min(max(ix0, 0), WW - 1), cx1 = min(max(ix1, 0), WW - 1);
            size_t ridx = ((size_t)(b * 9 + k) * HH + h) * WW + w2;
            off00[ridx] = cy0 * WW + cx0;
            off01[ridx] = cy0 * WW + cx1;
            off10[ridx] = cy1 * WW + cx0;
            off11[ridx] = cy1 * WW + cx1;
            ww00[ridx] = (vy0 && vx0) ? wy0 * wx0 * m : 0.f;
            ww01[ridx] = (vy0 && vx1) ? wy0 * wx1 * m : 0.f;
            ww10[ridx] = (vy1 && vx0) ? wy1 * wx0 * m : 0.f;
            ww11[ridx] = (vy1 && vx1) ? wy1 * wx1 * m : 0.f;
        }
    }
}

// ---------------------------------------------------------------------------
// K2: implicit GEMM. Block = 64 pixels (one (b,h) row) x 128 oc, Kc = 64.
//     A gathered on the fly (4 loads + 4 FMA per element), fp32 4x8 reg tile.
// ---------------------------------------------------------------------------
__global__ __launch_bounds__(256) void main_gemm(
    const float* __restrict__ x, const float* __restrict__ Bmat,
    const float* __restrict__ bias,
    const int* __restrict__ off00, const int* __restrict__ off01,
    const int* __restrict__ off10, const int* __restrict__ off11,
    const float* __restrict__ ww00, const float* __restrict__ ww01,
    const float* __restrict__ ww10, const float* __restrict__ ww11,
    float* __restrict__ out)
{
    __shared__ float A_lds[64][64];    // [k_local(c)][pixel]
    __shared__ float B_lds[64][128];   // [k_local][oc]

    int nb = blockIdx.x & 1;
    int pb = blockIdx.x >> 1;
    int b = pb >> 6, h = pb & 63;
    int t = threadIdx.x;
    int p = t & 63;          // staging pixel (lane)
    int cl4 = t >> 6;        // staging c-quarter (wave id)
    int oc0 = nb * 128;

    float acc[4][8];
    #pragma unroll
    for (int i = 0; i < 4; ++i)
        #pragma unroll
        for (int j = 0; j < 8; ++j) acc[i][j] = 0.f;

    const float* xb = x + (size_t)b * CIN * HW;
    const int pr0 = (t & 15) * 4;   // compute pixel base
    const int or0 = (t >> 4) * 8;   // compute oc base

    for (int tap = 0; tap < 9; ++tap) {
        size_t ridx = ((size_t)(b * 9 + tap) * HH + h) * WW + p;
        int o00 = off00[ridx], o01 = off01[ridx];
        int o10 = off10[ridx], o11 = off11[ridx];
        float f00 = ww00[ridx], f01 = ww01[ridx];
        float f10 = ww10[ridx], f11 = ww11[ridx];

        for (int cc = 0; cc < 4; ++cc) {
            // ---- stage A: 16 channels per thread, fixed pixel p ----
            #pragma unroll
            for (int i = 0; i < 16; ++i) {
                int cl = cl4 * 16 + i;
                const float* xs = xb + (size_t)(cc * 64 + cl) * HW;
                A_lds[cl][p] = f00 * xs[o00] + f01 * xs[o01]
                             + f10 * xs[o10] + f11 * xs[o11];
            }
            // ---- stage B: rows tap*256+cc*64 .. +63, cols oc0..oc0+127 ----
            {
                int krow0 = tap * 256 + cc * 64;
                #pragma unroll
                for (int j = 0; j < 8; ++j) {
                    int linear = t + j * 256;       // 0..2047 float4 slots
                    int row = linear >> 5;
                    int col4 = linear & 31;
                    float4 v = *reinterpret_cast<const float4*>(
                        &Bmat[(size_t)(krow0 + row) * 256 + oc0 + col4 * 4]);
                    *reinterpret_cast<float4*>(&B_lds[row][col4 * 4]) = v;
                }
            }
            __syncthreads();

            #pragma unroll 16
            for (int k = 0; k < 64; ++k) {
                float4 a4  = *reinterpret_cast<const float4*>(&A_lds[k][pr0]);
                float4 b4a = *reinterpret_cast<const float4*>(&B_lds[k][or0]);
                float4 b4b = *reinterpret_cast<const float4*>(&B_lds[k][or0 + 4]);
                float av[4] = {a4.x, a4.y, a4.z, a4.w};
                float bv[8] = {b4a.x, b4a.y, b4a.z, b4a.w,
                               b4b.x, b4b.y, b4b.z, b4b.w};
                #pragma unroll
                for (int i = 0; i < 4; ++i)
                    #pragma unroll
                    for (int j = 0; j < 8; ++j)
                        acc[i][j] = fmaf(av[i], bv[j], acc[i][j]);
            }
            __syncthreads();
        }
    }

    // epilogue: out[b][oc][h][pixel] + bias
    #pragma unroll
    for (int j = 0; j < 8; ++j) {
        int oc = oc0 + or0 + j;
        float bs = bias[oc];
        float4 v;
        v.x = acc[0][j] + bs;
        v.y = acc[1][j] + bs;
        v.z = acc[2][j] + bs;
        v.w = acc[3][j] + bs;
        *reinterpret_cast<float4*>(
            &out[((size_t)(b * 256 + oc) * HH + h) * WW + pr0]) = v;
    }
}

// ---------------------------------------------------------------------------
extern "C" void kernel_launch(void* const* d_in, const int* in_sizes, int n_in,
                              void* d_out, int out_size, void* d_ws, size_t ws_size,
                              hipStream_t stream) {
    const float* x        = (const float*)d_in[0];
    const float* weight   = (const float*)d_in[1];
    const float* bias     = (const float*)d_in[2];
    const float* offset_w = (const float*)d_in[3];
    const float* offset_b = (const float*)d_in[4];
    float* out = (float*)d_out;
    float* ws  = (float*)d_ws;

    float* Bmat = ws + WS_BMAT;
    float* rec  = ws + WS_REC;
    int*   off00 = (int*)(rec + 0 * (size_t)NPIX9);
    int*   off01 = (int*)(rec + 1 * (size_t)NPIX9);
    int*   off10 = (int*)(rec + 2 * (size_t)NPIX9);
    int*   off11 = (int*)(rec + 3 * (size_t)NPIX9);
    float* ww00  = rec + 4 * (size_t)NPIX9;
    float* ww01  = rec + 5 * (size_t)NPIX9;
    float* ww10  = rec + 6 * (size_t)NPIX9;
    float* ww11  = rec + 7 * (size_t)NPIX9;

    transpose_weights<<<2304, 256, 0, stream>>>(weight, Bmat);
    offset_conv<<<BB * HH, 256, 0, stream>>>(x, offset_w, offset_b,
                                             off00, off01, off10, off11,
                                             ww00, ww01, ww10, ww11);
    main_gemm<<<BB * HH * 2, 256, 0, stream>>>(x, Bmat, bias,
                                               off00, off01, off10, off11,
                                               ww00, ww01, ww10, ww11, out);
}

// Round 2
// 424.501 us; speedup vs baseline: 3.4831x; 3.4831x over previous
//
#include <hip/hip_runtime.h>
#include <math.h>

#define CIN 256
#define HH 64
#define WW 64
#define BB 8
#define HW 4096
#define KDIM 2304              // 9*256
#define NPIX9 (BB*9*HH*WW)     // 294912

typedef __attribute__((ext_vector_type(8))) short bf16x8;
typedef __attribute__((ext_vector_type(4))) float f32x4;

__device__ __forceinline__ unsigned short f2bf(float f) {
    unsigned int u = __float_as_uint(f);
    u += 0x7fffu + ((u >> 16) & 1u);
    return (unsigned short)(u >> 16);
}

#define GLDS16(gp, lp) __builtin_amdgcn_global_load_lds( \
    (const __attribute__((address_space(1))) unsigned int*)(gp), \
    (__attribute__((address_space(3))) unsigned int*)(lp), 16, 0, 0)

// ---------------------------------------------------------------------------
// K0a: main weight (Cout,Cin,3,3) -> Bsw[oc][k], k = tap*256+c, bf16,
//      pre-swizzled within each 64-element k-block: kc -> kc ^ ((oc&7)<<3)
// ---------------------------------------------------------------------------
__global__ __launch_bounds__(256) void pack_bsw(const float* __restrict__ weight,
                                                unsigned short* __restrict__ Bsw) {
    int oc = blockIdx.x;           // 0..255
    int c  = threadIdx.x;          // 0..255
    int cc = c >> 6, kc = c & 63;
    int swz = (oc & 7) << 3;
    const float* wp = weight + (size_t)oc * KDIM + c * 9;
    #pragma unroll
    for (int tap = 0; tap < 9; ++tap) {
        Bsw[(size_t)oc * KDIM + tap * 256 + cc * 64 + (kc ^ swz)] = f2bf(wp[tap]);
    }
}

// ---------------------------------------------------------------------------
// K0b: offset weight (27,Cin,3,3) -> B2sw[oc2][k], k = c*9+tap (natural),
//      rows 27..31 zero, same per-64 swizzle.
// ---------------------------------------------------------------------------
__global__ __launch_bounds__(256) void pack_b2(const float* __restrict__ ow,
                                               unsigned short* __restrict__ B2sw) {
    int oc = blockIdx.x;           // 0..31
    int c  = threadIdx.x;          // 0..255
    int swz = (oc & 7) << 3;
    #pragma unroll
    for (int tap = 0; tap < 9; ++tap) {
        int k = c * 9 + tap;
        int pos = (k & ~63) | ((k & 63) ^ swz);
        unsigned short v = 0;
        if (oc < 27) v = f2bf(ow[(size_t)oc * KDIM + k]);
        B2sw[(size_t)oc * KDIM + pos] = v;
    }
}

// ---------------------------------------------------------------------------
// K1: offset conv as MFMA GEMM (M=64 pixels/block, N=32(27), K=2304,
//     k = c*9+tap) + record build epilogue.
// ---------------------------------------------------------------------------
__global__ __launch_bounds__(256) void offset_gemm(
    const float* __restrict__ x, const unsigned short* __restrict__ B2sw,
    const float* __restrict__ ob,
    int* __restrict__ off00, int* __restrict__ off01,
    int* __restrict__ off10, int* __restrict__ off11,
    float* __restrict__ ww00, float* __restrict__ ww01,
    float* __restrict__ ww10, float* __restrict__ ww11)
{
    __shared__ unsigned short A_lds[64][64];   // [pixel][k], swizzled
    __shared__ unsigned short B2_lds[32][64];  // [oc][k], swizzled
    __shared__ float om[64][33];               // [pixel][oc], +1 pad

    const int blk = blockIdx.x;
    const int b = blk >> 6, h = blk & 63;
    const int t = threadIdx.x;
    const int p = t & 63;
    const int wv = t >> 6;
    const int ln = t & 63;

    f32x4 acc[2];
    #pragma unroll
    for (int n = 0; n < 2; ++n) acc[n] = (f32x4){0.f, 0.f, 0.f, 0.f};

    const float* xb = x + (size_t)b * CIN * HW;
    const int swzp = (p & 7) << 3;

    for (int ch = 0; ch < 36; ++ch) {
        const int k0 = ch * 64;
        __syncthreads();
        // stage B2 tile (4KB): one global_load_lds per wave
        {
            const unsigned short* gp = B2sw + (size_t)(wv * 8 + (ln >> 3)) * KDIM
                                     + k0 + (ln & 7) * 8;
            GLDS16(gp, &B2_lds[wv * 8][0]);
        }
        // stage A: thread builds 16 k-elements for pixel p
        #pragma unroll
        for (int g = 0; g < 2; ++g) {
            bf16x8 pk;
            #pragma unroll
            for (int i = 0; i < 8; ++i) {
                int k = k0 + wv * 16 + g * 8 + i;
                int c = (k * 7282) >> 16;          // k/9
                int tp = k - c * 9;
                int ki = (tp * 11) >> 5;           // tp/3
                int kj = tp - ki * 3;
                int yy = h - 1 + ki;
                int xx = p - 1 + kj;
                bool ok = ((unsigned)yy < 64u) && ((unsigned)xx < 64u);
                float v = ok ? xb[(size_t)c * HW + yy * WW + xx] : 0.f;
                pk[i] = (short)f2bf(v);
            }
            *(bf16x8*)&A_lds[p][(wv * 16 + g * 8) ^ swzp] = pk;
        }
        __syncthreads();
        #pragma unroll
        for (int ks = 0; ks < 2; ++ks) {
            const int kg = ks * 32 + ((ln >> 4) << 3);
            const int arow = wv * 16 + (ln & 15);
            bf16x8 af = *(const bf16x8*)&A_lds[arow][kg ^ ((arow & 7) << 3)];
            #pragma unroll
            for (int n = 0; n < 2; ++n) {
                const int brow = n * 16 + (ln & 15);
                bf16x8 bf = *(const bf16x8*)&B2_lds[brow][kg ^ ((brow & 7) << 3)];
                acc[n] = __builtin_amdgcn_mfma_f32_16x16x32_bf16(af, bf, acc[n], 0, 0, 0);
            }
        }
    }

    __syncthreads();
    #pragma unroll
    for (int n = 0; n < 2; ++n)
        #pragma unroll
        for (int r = 0; r < 4; ++r)
            om[wv * 16 + ((ln >> 4) << 2) + r][n * 16 + (ln & 15)] = acc[n][r];
    __syncthreads();

    for (int rep = 0; rep < 3; ++rep) {
        int idx = rep * 256 + t;   // 0..575 = 9 taps * 64 w
        if (idx < 576) {
            int k = idx >> 6, w2 = idx & 63;
            float dy = om[w2][2 * k]     + ob[2 * k];
            float dx = om[w2][2 * k + 1] + ob[2 * k + 1];
            float mv = om[w2][18 + k]    + ob[18 + k];
            float m = 1.f / (1.f + expf(-mv));

            float py = dy + (float)(h - 1 + k / 3);
            float px = dx + (float)(w2 - 1 + k % 3);
            float y0f = floorf(py), x0f = floorf(px);
            float wy1 = py - y0f, wx1 = px - x0f;
            float wy0 = 1.f - wy1, wx0 = 1.f - wx1;
            int iy0 = (int)y0f, ix0 = (int)x0f;
            int iy1 = iy0 + 1, ix1 = ix0 + 1;
            bool vy0 = (iy0 >= 0) & (iy0 < HH);
            bool vy1 = (iy1 >= 0) & (iy1 < HH);
            bool vx0 = (ix0 >= 0) & (ix0 < WW);
            bool vx1 = (ix1 >= 0) & (ix1 < WW);
            int cy0 = min(max(iy0, 0), HH - 1), cy1 = min(max(iy1, 0), HH - 1);
            int cx0 = min(max(ix0, 0), WW - 1), cx1 = min(max(ix1, 0), WW - 1);
            size_t ridx = ((size_t)(b * 9 + k) * HH + h) * WW + w2;
            off00[ridx] = cy0 * WW + cx0;
            off01[ridx] = cy0 * WW + cx1;
            off10[ridx] = cy1 * WW + cx0;
            off11[ridx] = cy1 * WW + cx1;
            ww00[ridx] = (vy0 && vx0) ? wy0 * wx0 * m : 0.f;
            ww01[ridx] = (vy0 && vx1) ? wy0 * wx1 * m : 0.f;
            ww10[ridx] = (vy1 && vx0) ? wy1 * wx0 * m : 0.f;
            ww11[ridx] = (vy1 && vx1) ? wy1 * wx1 * m : 0.f;
        }
    }
}

// ---------------------------------------------------------------------------
// K2: main implicit GEMM, MFMA 16x16x32 bf16.
//     Block = 64 pixels (one (b,h) row) x 256 oc, BK=64, 4 waves,
//     wave-tile 64x64. A gathered+packed to swizzled LDS; B staged via
//     global_load_lds from pre-swizzled Bsw.
// ---------------------------------------------------------------------------
__global__ __launch_bounds__(256, 2) void main_gemm(
    const float* __restrict__ x, const unsigned short* __restrict__ Bsw,
    const float* __restrict__ bias,
    const int* __restrict__ off00, const int* __restrict__ off01,
    const int* __restrict__ off10, const int* __restrict__ off11,
    const float* __restrict__ ww00, const float* __restrict__ ww01,
    const float* __restrict__ ww10, const float* __restrict__ ww11,
    float* __restrict__ out)
{
    __shared__ unsigned short A_lds[64][64];    // 8KB  [pixel][k] swizzled
    __shared__ unsigned short B_lds[256][64];   // 32KB [oc][k] swizzled

    const int blk = blockIdx.x;
    const int b = blk >> 6, h = blk & 63;
    const int t = threadIdx.x;
    const int p = t & 63;          // pixel lane
    const int wv = t >> 6;         // wave id
    const int ln = t & 63;

    f32x4 acc[4][4];
    #pragma unroll
    for (int m = 0; m < 4; ++m)
        #pragma unroll
        for (int n = 0; n < 4; ++n) acc[m][n] = (f32x4){0.f, 0.f, 0.f, 0.f};

    const float* xb = x + (size_t)b * CIN * HW;
    const int swzp = (p & 7) << 3;

    for (int tap = 0; tap < 9; ++tap) {
        const size_t ridx = ((size_t)(b * 9 + tap) * HH + h) * WW + p;
        const int o00 = off00[ridx], o01 = off01[ridx];
        const int o10 = off10[ridx], o11 = off11[ridx];
        const float f00 = ww00[ridx], f01 = ww01[ridx];
        const float f10 = ww10[ridx], f11 = ww11[ridx];

        for (int cc = 0; cc < 4; ++cc) {
            __syncthreads();   // prior compute done before LDS overwrite
            // ---- stage B (32KB): wave wv stages oc rows [wv*64, +64) ----
            {
                const unsigned short* gbase = Bsw + (size_t)(ln >> 3) * KDIM
                                            + tap * 256 + cc * 64 + (ln & 7) * 8;
                #pragma unroll
                for (int it = 0; it < 8; ++it) {
                    const int r0 = wv * 64 + it * 8;
                    GLDS16(gbase + (size_t)r0 * KDIM, &B_lds[r0][0]);
                }
            }
            // ---- stage A: wave's 16-channel quarter for pixel p ----
            {
                const float* xs = xb + (size_t)(cc * 64 + wv * 16) * HW;
                #pragma unroll
                for (int g = 0; g < 2; ++g) {
                    bf16x8 pk;
                    #pragma unroll
                    for (int i = 0; i < 8; ++i) {
                        float v = f00 * xs[o00] + f01 * xs[o01]
                                + f10 * xs[o10] + f11 * xs[o11];
                        pk[i] = (short)f2bf(v);
                        xs += HW;
                    }
                    *(bf16x8*)&A_lds[p][(wv * 16 + g * 8) ^ swzp] = pk;
                }
            }
            __syncthreads();
            // ---- MFMA: 2 k-steps x (4 A-frags, 4 B-frags, 16 MFMA) ----
            #pragma unroll
            for (int ks = 0; ks < 2; ++ks) {
                const int kg = ks * 32 + ((ln >> 4) << 3);
                bf16x8 af[4], bfr[4];
                #pragma unroll
                for (int m = 0; m < 4; ++m) {
                    const int row = m * 16 + (ln & 15);
                    af[m] = *(const bf16x8*)&A_lds[row][kg ^ ((row & 7) << 3)];
                }
                #pragma unroll
                for (int n = 0; n < 4; ++n) {
                    const int row = wv * 64 + n * 16 + (ln & 15);
                    bfr[n] = *(const bf16x8*)&B_lds[row][kg ^ ((row & 7) << 3)];
                }
                #pragma unroll
                for (int m = 0; m < 4; ++m)
                    #pragma unroll
                    for (int n = 0; n < 4; ++n)
                        acc[m][n] = __builtin_amdgcn_mfma_f32_16x16x32_bf16(
                            af[m], bfr[n], acc[m][n], 0, 0, 0);
            }
        }
    }

    // epilogue: D row = pixel (lane>>4)*4+reg, col = oc (lane&15)
    #pragma unroll
    for (int n = 0; n < 4; ++n) {
        const int oc = wv * 64 + n * 16 + (ln & 15);
        const float bs = bias[oc];
        float* orow = out + ((size_t)(b * 256 + oc) * HH + h) * WW;
        #pragma unroll
        for (int m = 0; m < 4; ++m) {
            f32x4 v = acc[m][n];
            float4 s;
            s.x = v[0] + bs; s.y = v[1] + bs; s.z = v[2] + bs; s.w = v[3] + bs;
            *(float4*)&orow[m * 16 + ((ln >> 4) << 2)] = s;
        }
    }
}

// ---------------------------------------------------------------------------
extern "C" void kernel_launch(void* const* d_in, const int* in_sizes, int n_in,
                              void* d_out, int out_size, void* d_ws, size_t ws_size,
                              hipStream_t stream) {
    const float* x        = (const float*)d_in[0];
    const float* weight   = (const float*)d_in[1];
    const float* bias     = (const float*)d_in[2];
    const float* offset_w = (const float*)d_in[3];
    const float* offset_b = (const float*)d_in[4];
    float* out = (float*)d_out;
    float* ws  = (float*)d_ws;

    unsigned short* Bsw  = (unsigned short*)ws;                   // 256*2304 u16
    unsigned short* B2sw = (unsigned short*)(ws + 294912);        // 32*2304 u16
    float* rec = ws + 294912 + 36864;
    int*   off00 = (int*)(rec + 0 * (size_t)NPIX9);
    int*   off01 = (int*)(rec + 1 * (size_t)NPIX9);
    int*   off10 = (int*)(rec + 2 * (size_t)NPIX9);
    int*   off11 = (int*)(rec + 3 * (size_t)NPIX9);
    float* ww00  = rec + 4 * (size_t)NPIX9;
    float* ww01  = rec + 5 * (size_t)NPIX9;
    float* ww10  = rec + 6 * (size_t)NPIX9;
    float* ww11  = rec + 7 * (size_t)NPIX9;

    pack_bsw<<<256, 256, 0, stream>>>(weight, Bsw);
    pack_b2<<<32, 256, 0, stream>>>(offset_w, B2sw);
    offset_gemm<<<BB * HH, 256, 0, stream>>>(x, B2sw, offset_b,
                                             off00, off01, off10, off11,
                                             ww00, ww01, ww10, ww11);
    main_gemm<<<BB * HH, 256, 0, stream>>>(x, Bsw, bias,
                                           off00, off01, off10, off11,
                                           ww00, ww01, ww10, ww11, out);
}

// Round 3
// 342.392 us; speedup vs baseline: 4.3184x; 1.2398x over previous
//
#include <hip/hip_runtime.h>
#include <math.h>

#define CIN 256
#define HH 64
#define WW 64
#define BB 8
#define HW 4096
#define KDIM 2304              // 9*256
#define NPIX9 (BB*9*HH*WW)     // 294912

typedef __attribute__((ext_vector_type(8))) short bf16x8;
typedef __attribute__((ext_vector_type(4))) float f32x4;

__device__ __forceinline__ unsigned short f2bf(float f) {
    unsigned int u = __float_as_uint(f);
    u += 0x7fffu + ((u >> 16) & 1u);
    return (unsigned short)(u >> 16);
}

#define GLDS16(gp, lp) __builtin_amdgcn_global_load_lds( \
    (const __attribute__((address_space(1))) unsigned int*)(gp), \
    (__attribute__((address_space(3))) unsigned int*)(lp), 16, 0, 0)

// ---------------------------------------------------------------------------
// K0a: main weight (Cout,Cin,3,3) -> Bsw[oc][k], k = tap*256+c, bf16,
//      pre-swizzled within each 64-element k-block: kc -> kc ^ ((oc&7)<<3)
// ---------------------------------------------------------------------------
__global__ __launch_bounds__(256) void pack_bsw(const float* __restrict__ weight,
                                                unsigned short* __restrict__ Bsw) {
    int oc = blockIdx.x;           // 0..255
    int c  = threadIdx.x;          // 0..255
    int cc = c >> 6, kc = c & 63;
    int swz = (oc & 7) << 3;
    const float* wp = weight + (size_t)oc * KDIM + c * 9;
    #pragma unroll
    for (int tap = 0; tap < 9; ++tap) {
        Bsw[(size_t)oc * KDIM + tap * 256 + cc * 64 + (kc ^ swz)] = f2bf(wp[tap]);
    }
}

// ---------------------------------------------------------------------------
// K0b: offset weight (27,Cin,3,3) -> B2sw[oc2][k], k = tap*256+c (tap-major!),
//      rows 27..31 zero, same per-64 swizzle.
// ---------------------------------------------------------------------------
__global__ __launch_bounds__(256) void pack_b2(const float* __restrict__ ow,
                                               unsigned short* __restrict__ B2sw) {
    int oc = blockIdx.x;           // 0..31
    int c  = threadIdx.x;          // 0..255
    int cc = c >> 6, kc = c & 63;
    int swz = (oc & 7) << 3;
    #pragma unroll
    for (int tap = 0; tap < 9; ++tap) {
        unsigned short v = 0;
        if (oc < 27) v = f2bf(ow[(size_t)oc * KDIM + c * 9 + tap]);
        B2sw[(size_t)oc * KDIM + tap * 256 + cc * 64 + (kc ^ swz)] = v;
    }
}

// ---------------------------------------------------------------------------
// K1: offset conv as MFMA GEMM. BM=128 (2 rows), N=32(27), K=2304 tap-major.
//     8 waves, double-buffered 2-phase, records epilogue.
// ---------------------------------------------------------------------------
__global__ __launch_bounds__(512, 1) void offset_gemm(
    const float* __restrict__ x, const unsigned short* __restrict__ B2sw,
    const float* __restrict__ ob,
    int* __restrict__ off00, int* __restrict__ off01,
    int* __restrict__ off10, int* __restrict__ off11,
    float* __restrict__ ww00, float* __restrict__ ww01,
    float* __restrict__ ww10, float* __restrict__ ww11)
{
    __shared__ unsigned short A_lds[2][128][64];   // 32KB
    __shared__ unsigned short B2_lds[2][32][64];   // 8KB
    __shared__ float om[128][33];                  // 16.9KB

    const int mb = blockIdx.x;     // 0..255
    const int b = mb & 7;          // XCD-locality: one image per XCD
    const int h0 = (mb >> 3) * 2;
    const int t = threadIdx.x;
    const int wv = t >> 6, ln = t & 63;
    const int p = t & 127;         // staging pixel
    const int oct0 = t >> 7;       // 0..3
    const int hP = h0 + (p >> 6), wP = p & 63;
    const int swzp = (p & 7) << 3;

    f32x4 acc[2];
    acc[0] = (f32x4){0.f,0.f,0.f,0.f};
    acc[1] = (f32x4){0.f,0.f,0.f,0.f};

    const float* xb = x + (size_t)b * CIN * HW;

    // ---- prologue: stage step 0 (tap0, cc0) into buf 0 ----
    {
        if (wv < 4) {
            const unsigned short* gp = B2sw + (size_t)(wv * 8 + (ln >> 3)) * KDIM
                                     + (ln & 7) * 8;
            GLDS16(gp, &B2_lds[0][wv * 8][0]);
        }
        int y = hP - 1, xx = wP - 1;
        bool ok = ((unsigned)y < 64u) & ((unsigned)xx < 64u);
        const float* bp = xb + (y * WW + xx);
        #pragma unroll
        for (int g = 0; g < 2; ++g) {
            const int k8 = oct0 * 8 + g * 32;
            bf16x8 pk;
            #pragma unroll
            for (int i = 0; i < 8; ++i) {
                float v = ok ? bp[(size_t)(k8 + i) * HW] : 0.f;
                pk[i] = (short)f2bf(v);
            }
            *(bf16x8*)&A_lds[0][p][k8 ^ swzp] = pk;
        }
    }
    __syncthreads();

    for (int kk = 0; kk < 36; ++kk) {
        const int cur = kk & 1;
        const bool pre = kk < 35;
        float xr[16];
        if (pre) {
            const int kn = kk + 1, tapn = kn >> 2, ccn = kn & 3;
            if (wv < 4) {
                const unsigned short* gp = B2sw + (size_t)(wv * 8 + (ln >> 3)) * KDIM
                                         + tapn * 256 + ccn * 64 + (ln & 7) * 8;
                GLDS16(gp, &B2_lds[cur ^ 1][wv * 8][0]);
            }
            const int ki = (tapn * 11) >> 5, kj = tapn - ki * 3;
            int y = hP - 1 + ki, xx = wP - 1 + kj;
            bool ok = ((unsigned)y < 64u) & ((unsigned)xx < 64u);
            const float* bp = xb + (size_t)(ccn * 64) * HW + (y * WW + xx);
            #pragma unroll
            for (int g = 0; g < 2; ++g)
                #pragma unroll
                for (int i = 0; i < 8; ++i)
                    xr[g * 8 + i] = ok ? bp[(size_t)(oct0 * 8 + g * 32 + i) * HW] : 0.f;
        }
        // compute(cur)
        #pragma unroll
        for (int ks = 0; ks < 2; ++ks) {
            const int kg = ks * 32 + ((ln >> 4) << 3);
            const int ar = wv * 16 + (ln & 15);
            bf16x8 af = *(const bf16x8*)&A_lds[cur][ar][kg ^ ((ar & 7) << 3)];
            #pragma unroll
            for (int n = 0; n < 2; ++n) {
                const int br = n * 16 + (ln & 15);
                bf16x8 bfr = *(const bf16x8*)&B2_lds[cur][br][kg ^ ((br & 7) << 3)];
                acc[n] = __builtin_amdgcn_mfma_f32_16x16x32_bf16(af, bfr, acc[n], 0, 0, 0);
            }
        }
        if (pre) {
            #pragma unroll
            for (int g = 0; g < 2; ++g) {
                const int k8 = oct0 * 8 + g * 32;
                bf16x8 pk;
                #pragma unroll
                for (int i = 0; i < 8; ++i) pk[i] = (short)f2bf(xr[g * 8 + i]);
                *(bf16x8*)&A_lds[cur ^ 1][p][k8 ^ swzp] = pk;
            }
        }
        __syncthreads();
    }

    #pragma unroll
    for (int n = 0; n < 2; ++n)
        #pragma unroll
        for (int r = 0; r < 4; ++r)
            om[wv * 16 + ((ln >> 4) << 2) + r][n * 16 + (ln & 15)] = acc[n][r];
    __syncthreads();

    #pragma unroll
    for (int rep = 0; rep < 3; ++rep) {
        int idx = rep * 512 + t;   // 0..1151 = 9 taps * 128 pixels
        if (idx < 1152) {
            int k = idx >> 7, p2 = idx & 127;
            int h = h0 + (p2 >> 6), w2 = p2 & 63;
            float dy = om[p2][2 * k]     + ob[2 * k];
            float dx = om[p2][2 * k + 1] + ob[2 * k + 1];
            float mv = om[p2][18 + k]    + ob[18 + k];
            float m = 1.f / (1.f + expf(-mv));

            float py = dy + (float)(h - 1 + k / 3);
            float px = dx + (float)(w2 - 1 + k % 3);
            float y0f = floorf(py), x0f = floorf(px);
            float wy1 = py - y0f, wx1 = px - x0f;
            float wy0 = 1.f - wy1, wx0 = 1.f - wx1;
            int iy0 = (int)y0f, ix0 = (int)x0f;
            int iy1 = iy0 + 1, ix1 = ix0 + 1;
            bool vy0 = (iy0 >= 0) & (iy0 < HH);
            bool vy1 = (iy1 >= 0) & (iy1 < HH);
            bool vx0 = (ix0 >= 0) & (ix0 < WW);
            bool vx1 = (ix1 >= 0) & (ix1 < WW);
            int cy0 = min(max(iy0, 0), HH - 1), cy1 = min(max(iy1, 0), HH - 1);
            int cx0 = min(max(ix0, 0), WW - 1), cx1 = min(max(ix1, 0), WW - 1);
            size_t ridx = ((size_t)(b * 9 + k) * HH + h) * WW + w2;
            off00[ridx] = cy0 * WW + cx0;
            off01[ridx] = cy0 * WW + cx1;
            off10[ridx] = cy1 * WW + cx0;
            off11[ridx] = cy1 * WW + cx1;
            ww00[ridx] = (vy0 && vx0) ? wy0 * wx0 * m : 0.f;
            ww01[ridx] = (vy0 && vx1) ? wy0 * wx1 * m : 0.f;
            ww10[ridx] = (vy1 && vx0) ? wy1 * wx0 * m : 0.f;
            ww11[ridx] = (vy1 && vx1) ? wy1 * wx1 * m : 0.f;
        }
    }
}

// ---------------------------------------------------------------------------
// K2: main implicit GEMM, MFMA 16x16x32 bf16.
//     BM=128 pixels (2 rows), BN=256 oc, BK=64, 8 waves (2Mx4N), dbuf LDS,
//     2-phase pipeline with async-split A gather (issue early / pack late).
// ---------------------------------------------------------------------------
__global__ __launch_bounds__(512, 1) void main_gemm(
    const float* __restrict__ x, const unsigned short* __restrict__ Bsw,
    const float* __restrict__ bias,
    const int* __restrict__ off00, const int* __restrict__ off01,
    const int* __restrict__ off10, const int* __restrict__ off11,
    const float* __restrict__ ww00, const float* __restrict__ ww01,
    const float* __restrict__ ww10, const float* __restrict__ ww11,
    float* __restrict__ out)
{
    __shared__ unsigned short A_lds[2][128][64];    // 32KB
    __shared__ unsigned short B_lds[2][256][64];    // 64KB

    const int mb = blockIdx.x;     // 0..255
    const int b = mb & 7;          // XCD-locality: one image per XCD
    const int h0 = (mb >> 3) * 2;
    const int t = threadIdx.x;
    const int wv = t >> 6, ln = t & 63;
    const int wm = wv >> 2, wn = wv & 3;   // 2 x 4 wave grid
    const int p = t & 127;         // staging pixel
    const int oct0 = t >> 7;       // 0..3
    const int hP = h0 + (p >> 6), wP = p & 63;
    const int swzp = (p & 7) << 3;

    f32x4 acc[4][4];
    #pragma unroll
    for (int m = 0; m < 4; ++m)
        #pragma unroll
        for (int n = 0; n < 4; ++n) acc[m][n] = (f32x4){0.f,0.f,0.f,0.f};

    const float* xb = x + (size_t)b * CIN * HW;

    // ---- prologue: stage step 0 (tap0, cc0) into buf 0 ----
    {
        const unsigned short* gb = Bsw + (size_t)(ln >> 3) * KDIM + (ln & 7) * 8;
        #pragma unroll
        for (int it = 0; it < 4; ++it) {
            const int r0 = wv * 32 + it * 8;
            GLDS16(gb + (size_t)r0 * KDIM, &B_lds[0][r0][0]);
        }
        const size_t ridx = ((size_t)(b * 9) * HH + hP) * WW + wP;
        const int o00 = off00[ridx], o01 = off01[ridx];
        const int o10 = off10[ridx], o11 = off11[ridx];
        const float f00 = ww00[ridx], f01 = ww01[ridx];
        const float f10 = ww10[ridx], f11 = ww11[ridx];
        #pragma unroll
        for (int g = 0; g < 2; ++g) {
            const int k8 = oct0 * 8 + g * 32;
            bf16x8 pk;
            #pragma unroll
            for (int i = 0; i < 8; ++i) {
                const float* xs = xb + (size_t)(k8 + i) * HW;
                float v = f00 * xs[o00] + f01 * xs[o01]
                        + f10 * xs[o10] + f11 * xs[o11];
                pk[i] = (short)f2bf(v);
            }
            *(bf16x8*)&A_lds[0][p][k8 ^ swzp] = pk;
        }
    }
    __syncthreads();

    for (int kk = 0; kk < 36; ++kk) {
        const int cur = kk & 1;
        const bool pre = kk < 35;
        float c00[16], c01[16], c10[16], c11[16];
        float f00 = 0.f, f01 = 0.f, f10 = 0.f, f11 = 0.f;
        int o00 = 0, o01 = 0, o10 = 0, o11 = 0;
        const float* xc = xb;
        if (pre) {
            const int kn = kk + 1, tapn = kn >> 2, ccn = kn & 3;
            const unsigned short* gb = Bsw + (size_t)(ln >> 3) * KDIM
                                     + tapn * 256 + ccn * 64 + (ln & 7) * 8;
            #pragma unroll
            for (int it = 0; it < 4; ++it) {
                const int r0 = wv * 32 + it * 8;
                GLDS16(gb + (size_t)r0 * KDIM, &B_lds[cur ^ 1][r0][0]);
            }
            const size_t ridx = ((size_t)(b * 9 + tapn) * HH + hP) * WW + wP;
            o00 = off00[ridx]; o01 = off01[ridx];
            o10 = off10[ridx]; o11 = off11[ridx];
            f00 = ww00[ridx]; f01 = ww01[ridx];
            f10 = ww10[ridx]; f11 = ww11[ridx];
            xc = xb + (size_t)(ccn * 64 + oct0 * 8) * HW;
            #pragma unroll
            for (int i = 0; i < 8; ++i) {       // issue g0 gather
                const float* xs = xc + (size_t)i * HW;
                c00[i] = xs[o00]; c01[i] = xs[o01];
                c10[i] = xs[o10]; c11[i] = xs[o11];
            }
        }
        // ---- MFMA ks=0 (overlaps g0 gather + B GLDS) ----
        {
            const int kg = (ln >> 4) << 3;
            bf16x8 af[4], bfr[4];
            #pragma unroll
            for (int m = 0; m < 4; ++m) {
                const int row = wm * 64 + m * 16 + (ln & 15);
                af[m] = *(const bf16x8*)&A_lds[cur][row][kg ^ ((row & 7) << 3)];
            }
            #pragma unroll
            for (int n = 0; n < 4; ++n) {
                const int row = wn * 64 + n * 16 + (ln & 15);
                bfr[n] = *(const bf16x8*)&B_lds[cur][row][kg ^ ((row & 7) << 3)];
            }
            #pragma unroll
            for (int m = 0; m < 4; ++m)
                #pragma unroll
                for (int n = 0; n < 4; ++n)
                    acc[m][n] = __builtin_amdgcn_mfma_f32_16x16x32_bf16(
                        af[m], bfr[n], acc[m][n], 0, 0, 0);
        }
        if (pre) {
            // pack g0 -> LDS, then issue g1 gather
            bf16x8 pk;
            #pragma unroll
            for (int i = 0; i < 8; ++i) {
                float v = f00 * c00[i] + f01 * c01[i]
                        + f10 * c10[i] + f11 * c11[i];
                pk[i] = (short)f2bf(v);
            }
            *(bf16x8*)&A_lds[cur ^ 1][p][(oct0 * 8) ^ swzp] = pk;
            const float* xc1 = xc + (size_t)32 * HW;
            #pragma unroll
            for (int i = 0; i < 8; ++i) {
                const float* xs = xc1 + (size_t)i * HW;
                c00[8 + i] = xs[o00]; c01[8 + i] = xs[o01];
                c10[8 + i] = xs[o10]; c11[8 + i] = xs[o11];
            }
        }
        // ---- MFMA ks=1 (overlaps g1 gather) ----
        {
            const int kg = 32 + ((ln >> 4) << 3);
            bf16x8 af[4], bfr[4];
            #pragma unroll
            for (int m = 0; m < 4; ++m) {
                const int row = wm * 64 + m * 16 + (ln & 15);
                af[m] = *(const bf16x8*)&A_lds[cur][row][kg ^ ((row & 7) << 3)];
            }
            #pragma unroll
            for (int n = 0; n < 4; ++n) {
                const int row = wn * 64 + n * 16 + (ln & 15);
                bfr[n] = *(const bf16x8*)&B_lds[cur][row][kg ^ ((row & 7) << 3)];
            }
            #pragma unroll
            for (int m = 0; m < 4; ++m)
                #pragma unroll
                for (int n = 0; n < 4; ++n)
                    acc[m][n] = __builtin_amdgcn_mfma_f32_16x16x32_bf16(
                        af[m], bfr[n], acc[m][n], 0, 0, 0);
        }
        if (pre) {
            bf16x8 pk;
            #pragma unroll
            for (int i = 0; i < 8; ++i) {
                float v = f00 * c00[8 + i] + f01 * c01[8 + i]
                        + f10 * c10[8 + i] + f11 * c11[8 + i];
                pk[i] = (short)f2bf(v);
            }
            *(bf16x8*)&A_lds[cur ^ 1][p][(oct0 * 8 + 32) ^ swzp] = pk;
        }
        __syncthreads();
    }

    // epilogue: D row = pixel (ln>>4)*4+reg, col = oc (ln&15)
    #pragma unroll
    for (int n = 0; n < 4; ++n) {
        const int oc = wn * 64 + n * 16 + (ln & 15);
        const float bs = bias[oc];
        #pragma unroll
        for (int m = 0; m < 4; ++m) {
            const int pix = wm * 64 + m * 16 + ((ln >> 4) << 2);
            const int h = h0 + (pix >> 6), w0 = pix & 63;
            f32x4 v = acc[m][n];
            float4 s;
            s.x = v[0] + bs; s.y = v[1] + bs; s.z = v[2] + bs; s.w = v[3] + bs;
            *(float4*)&out[((size_t)(b * 256 + oc) * HH + h) * WW + w0] = s;
        }
    }
}

// ---------------------------------------------------------------------------
extern "C" void kernel_launch(void* const* d_in, const int* in_sizes, int n_in,
                              void* d_out, int out_size, void* d_ws, size_t ws_size,
                              hipStream_t stream) {
    const float* x        = (const float*)d_in[0];
    const float* weight   = (const float*)d_in[1];
    const float* bias     = (const float*)d_in[2];
    const float* offset_w = (const float*)d_in[3];
    const float* offset_b = (const float*)d_in[4];
    float* out = (float*)d_out;
    float* ws  = (float*)d_ws;

    unsigned short* Bsw  = (unsigned short*)ws;                   // 256*2304 u16
    unsigned short* B2sw = (unsigned short*)(ws + 294912);        // 32*2304 u16
    float* rec = ws + 294912 + 36864;
    int*   off00 = (int*)(rec + 0 * (size_t)NPIX9);
    int*   off01 = (int*)(rec + 1 * (size_t)NPIX9);
    int*   off10 = (int*)(rec + 2 * (size_t)NPIX9);
    int*   off11 = (int*)(rec + 3 * (size_t)NPIX9);
    float* ww00  = rec + 4 * (size_t)NPIX9;
    float* ww01  = rec + 5 * (size_t)NPIX9;
    float* ww10  = rec + 6 * (size_t)NPIX9;
    float* ww11  = rec + 7 * (size_t)NPIX9;

    pack_bsw<<<256, 256, 0, stream>>>(weight, Bsw);
    pack_b2<<<32, 256, 0, stream>>>(offset_w, B2sw);
    offset_gemm<<<256, 512, 0, stream>>>(x, B2sw, offset_b,
                                         off00, off01, off10, off11,
                                         ww00, ww01, ww10, ww11);
    main_gemm<<<256, 512, 0, stream>>>(x, Bsw, bias,
                                       off00, off01, off10, off11,
                                       ww00, ww01, ww10, ww11, out);
}